// Round 5
// baseline (274.558 us; speedup 1.0000x reference)
//
#include <hip/hip_runtime.h>
#include <hip/hip_bf16.h>
#include <hip/hip_fp16.h>
#include <math.h>

typedef _Float16 f16;
typedef _Float16 f16x8 __attribute__((ext_vector_type(8)));
typedef _Float16 f16x4 __attribute__((ext_vector_type(4)));
typedef _Float16 f16x2 __attribute__((ext_vector_type(2)));
typedef unsigned short u16x8v __attribute__((ext_vector_type(8)));
typedef float f32x4 __attribute__((ext_vector_type(4)));

namespace {
constexpr int B = 2;
constexpr int H = 16;
constexpr int S = 2048;
constexpr int D = 64;
constexpr int E = 1024;
constexpr int LP = 72;   // LDS row stride (f16) for P scratch / transpose tiles
constexpr float QSCALE = 0.125f * 1.4426950408889634f;  // 1/sqrt(64) * log2(e)
}

// ---------- Wkv = Wk*Wv, bkv = Wk*bv + bk  (fp32, tiny)
__global__ void make_wkv(const float* __restrict__ Wk, const float* __restrict__ Wv,
                         const float* __restrict__ bv, const float* __restrict__ bk,
                         float* __restrict__ Wkv, float* __restrict__ bkv) {
  const int g = blockIdx.x * 256 + threadIdx.x;   // 0..4095
  const int i = g >> 6, j = g & 63;
  float s = 0.f;
#pragma unroll 16
  for (int d = 0; d < 64; ++d) s = fmaf(Wk[i * 64 + d], Wv[d * 64 + j], s);
  Wkv[g] = s;
  if (g < 64) {
    float bb = bk[g];
#pragma unroll 16
    for (int d = 0; d < 64; ++d) bb = fmaf(Wk[g * 64 + d], bv[d], bb);
    bkv[g] = bb;
  }
}

// ---------- Wd fp32 -> f16
__global__ __launch_bounds__(256) void cvt_wd(const float* __restrict__ W, f16* __restrict__ out) {
  const int i = blockIdx.x * 256 + threadIdx.x;
  const float4 f = ((const float4*)W)[i];
  f16x4 o;
  o.x = (f16)f.x; o.y = (f16)f.y; o.z = (f16)f.z; o.w = (f16)f.w;
  *(f16x4*)(out + 4 * (size_t)i) = o;
}

// ---------- q projection: one-shot MFMA GEMM (M=65536, K=64, N=64), scale folded
__global__ __launch_bounds__(256) void proj_mfma(const float* __restrict__ x,
                                                 const float* __restrict__ W,
                                                 const float* __restrict__ bias,
                                                 f16* __restrict__ out, float scale) {
  const int t = threadIdx.x, lane = t & 63, w = t >> 6;
  const int l15 = lane & 15, quad = lane >> 4;
  const int m0 = (blockIdx.x * 4 + w) * 64;

  f16x8 wf[4][2], af[4][2];
#pragma unroll
  for (int nt = 0; nt < 4; ++nt)
#pragma unroll
    for (int kc = 0; kc < 2; ++kc) {
      const float* g = W + (size_t)(nt * 16 + l15) * 64 + kc * 32 + quad * 8;
      const float4 a = *(const float4*)g, b2 = *(const float4*)(g + 4);
      f16x8 v;
      v[0]=(f16)a.x; v[1]=(f16)a.y; v[2]=(f16)a.z; v[3]=(f16)a.w;
      v[4]=(f16)b2.x; v[5]=(f16)b2.y; v[6]=(f16)b2.z; v[7]=(f16)b2.w;
      wf[nt][kc] = v;
    }
#pragma unroll
  for (int mt = 0; mt < 4; ++mt)
#pragma unroll
    for (int kc = 0; kc < 2; ++kc) {
      const float* g = x + (size_t)(m0 + mt * 16 + l15) * 64 + kc * 32 + quad * 8;
      const float4 a = *(const float4*)g, b2 = *(const float4*)(g + 4);
      f16x8 v;
      v[0]=(f16)a.x; v[1]=(f16)a.y; v[2]=(f16)a.z; v[3]=(f16)a.w;
      v[4]=(f16)b2.x; v[5]=(f16)b2.y; v[6]=(f16)b2.z; v[7]=(f16)b2.w;
      af[mt][kc] = v;
    }

  f32x4 acc[4][4];
#pragma unroll
  for (int mt = 0; mt < 4; ++mt)
#pragma unroll
    for (int nt = 0; nt < 4; ++nt) acc[mt][nt] = (f32x4){0.f, 0.f, 0.f, 0.f};
#pragma unroll
  for (int kc = 0; kc < 2; ++kc)
#pragma unroll
    for (int nt = 0; nt < 4; ++nt)
#pragma unroll
      for (int mt = 0; mt < 4; ++mt)
        acc[mt][nt] = __builtin_amdgcn_mfma_f32_16x16x32_f16(af[mt][kc], wf[nt][kc], acc[mt][nt], 0, 0, 0);

  float bl[4];
#pragma unroll
  for (int nt = 0; nt < 4; ++nt) bl[nt] = bias[nt * 16 + l15];

#pragma unroll
  for (int mt = 0; mt < 4; ++mt)
#pragma unroll
    for (int r = 0; r < 4; ++r) {
      const int g = m0 + mt * 16 + quad * 4 + r;   // (b*S+s)*H + h
      const int h = g & 15, bs = g >> 4;
      const int b = bs >> 11, s = bs & 2047;
      f16* o = out + ((size_t)(b * H + h) * S + s) * 64;
#pragma unroll
      for (int nt = 0; nt < 4; ++nt)
        o[nt * 16 + l15] = (f16)((acc[mt][nt][r] + bl[nt]) * scale);
    }
}

// ---------- fused v & k projections sharing A-frags (k = x·Wkv^T + bkv == quirk)
__global__ __launch_bounds__(256) void proj_vk_mfma(const float* __restrict__ x,
                                                    const float* __restrict__ Wv,
                                                    const float* __restrict__ bv,
                                                    const float* __restrict__ Wkv,
                                                    const float* __restrict__ bkv,
                                                    f16* __restrict__ vout,
                                                    f16* __restrict__ kout) {
  const int t = threadIdx.x, lane = t & 63, w = t >> 6;
  const int l15 = lane & 15, quad = lane >> 4;
  const int m0 = (blockIdx.x * 4 + w) * 32;

  f16x8 wfv[4][2], wfk[4][2], af[2][2];
#pragma unroll
  for (int nt = 0; nt < 4; ++nt)
#pragma unroll
    for (int kc = 0; kc < 2; ++kc) {
      const size_t off = (size_t)(nt * 16 + l15) * 64 + kc * 32 + quad * 8;
      {
        const float4 a = *(const float4*)(Wv + off), b2 = *(const float4*)(Wv + off + 4);
        f16x8 v;
        v[0]=(f16)a.x; v[1]=(f16)a.y; v[2]=(f16)a.z; v[3]=(f16)a.w;
        v[4]=(f16)b2.x; v[5]=(f16)b2.y; v[6]=(f16)b2.z; v[7]=(f16)b2.w;
        wfv[nt][kc] = v;
      }
      {
        const float4 a = *(const float4*)(Wkv + off), b2 = *(const float4*)(Wkv + off + 4);
        f16x8 v;
        v[0]=(f16)a.x; v[1]=(f16)a.y; v[2]=(f16)a.z; v[3]=(f16)a.w;
        v[4]=(f16)b2.x; v[5]=(f16)b2.y; v[6]=(f16)b2.z; v[7]=(f16)b2.w;
        wfk[nt][kc] = v;
      }
    }
#pragma unroll
  for (int mt = 0; mt < 2; ++mt)
#pragma unroll
    for (int kc = 0; kc < 2; ++kc) {
      const float* g = x + (size_t)(m0 + mt * 16 + l15) * 64 + kc * 32 + quad * 8;
      const float4 a = *(const float4*)g, b2 = *(const float4*)(g + 4);
      f16x8 v;
      v[0]=(f16)a.x; v[1]=(f16)a.y; v[2]=(f16)a.z; v[3]=(f16)a.w;
      v[4]=(f16)b2.x; v[5]=(f16)b2.y; v[6]=(f16)b2.z; v[7]=(f16)b2.w;
      af[mt][kc] = v;
    }

  f32x4 accv[2][4], acck[2][4];
#pragma unroll
  for (int mt = 0; mt < 2; ++mt)
#pragma unroll
    for (int nt = 0; nt < 4; ++nt) {
      accv[mt][nt] = (f32x4){0.f, 0.f, 0.f, 0.f};
      acck[mt][nt] = (f32x4){0.f, 0.f, 0.f, 0.f};
    }
#pragma unroll
  for (int kc = 0; kc < 2; ++kc)
#pragma unroll
    for (int nt = 0; nt < 4; ++nt)
#pragma unroll
      for (int mt = 0; mt < 2; ++mt) {
        accv[mt][nt] = __builtin_amdgcn_mfma_f32_16x16x32_f16(af[mt][kc], wfv[nt][kc], accv[mt][nt], 0, 0, 0);
        acck[mt][nt] = __builtin_amdgcn_mfma_f32_16x16x32_f16(af[mt][kc], wfk[nt][kc], acck[mt][nt], 0, 0, 0);
      }

  float blv[4], blk[4];
#pragma unroll
  for (int nt = 0; nt < 4; ++nt) { blv[nt] = bv[nt * 16 + l15]; blk[nt] = bkv[nt * 16 + l15]; }

#pragma unroll
  for (int mt = 0; mt < 2; ++mt)
#pragma unroll
    for (int r = 0; r < 4; ++r) {
      const int g = m0 + mt * 16 + quad * 4 + r;
      const int h = g & 15, bs = g >> 4;
      const int b = bs >> 11, s = bs & 2047;
      const size_t o = ((size_t)(b * H + h) * S + s) * 64;
#pragma unroll
      for (int nt = 0; nt < 4; ++nt) {
        vout[o + nt * 16 + l15] = (f16)(accv[mt][nt][r] + blv[nt]);
        kout[o + nt * 16 + l15] = (f16)(acck[mt][nt][r] + blk[nt]);
      }
    }
}

// ---------- V transpose: vp[bh][s][d] -> vtg[bh][d][kt*64 + p], kv(p) = (p&3)*16 + (p>>2)
__global__ __launch_bounds__(256) void transpose_v(const f16* __restrict__ vp,
                                                   f16* __restrict__ vtg) {
  __shared__ f16 lvt[64 * LP];
  const int t = threadIdx.x;
  const int bh = blockIdx.x, kt = blockIdx.y;
  const f16* vb = vp + ((size_t)bh * S + kt * 64) * D;
  {
    const int d0 = (t >> 5) * 8, pc0 = (t & 31) * 2;
    const int kva = (pc0 & 3) * 16 + (pc0 >> 2);
    const u16x8v a = *(const u16x8v*)(vb + (size_t)kva * D + d0);
    const u16x8v b2 = *(const u16x8v*)(vb + (size_t)(kva + 16) * D + d0);
#pragma unroll
    for (int j = 0; j < 8; ++j) {
      const unsigned pk = (unsigned)a[j] | ((unsigned)b2[j] << 16);
      *(unsigned*)&lvt[(d0 + j) * LP + pc0] = pk;
    }
  }
  __syncthreads();
  const int d = t >> 2, pc = (t & 3) * 16;
  f16* o = vtg + ((size_t)bh * D + d) * S + kt * 64 + pc;
  *(f16x8*)o = *(const f16x8*)&lvt[d * LP + pc];
  *(f16x8*)(o + 8) = *(const f16x8*)&lvt[d * LP + pc + 8];
}

// ---------- MFMA flash attention, barrier-free: K + V^T frags direct from global,
// only P round-trips through per-wave LDS. No-max softmax (scores |.|<~9 safe in f16 exp2).
__global__ __launch_bounds__(256, 2) void attn_mfma(const f16* __restrict__ qp,
                                                    const f16* __restrict__ kp,
                                                    const f16* __restrict__ vtg,
                                                    f16* __restrict__ ao) {
  __shared__ f16 ps[4 * 32 * LP];   // per-wave P scratch [32 q][64 p]
  const int t = threadIdx.x, lane = t & 63, w = t >> 6;
  const int l15 = lane & 15, quad = lane >> 4;
  const int bh = blockIdx.x;
  const int q0 = blockIdx.y * 128;
  const f16* qbase = qp + ((size_t)bh * S + q0 + w * 32) * D;
  const f16* kbase = kp + (size_t)bh * S * D;
  const f16* vbase = vtg + (size_t)bh * D * S;
  f16* pw = ps + w * 32 * LP;

  f16x8 qf[2][2];
#pragma unroll
  for (int mt = 0; mt < 2; ++mt)
#pragma unroll
    for (int kc = 0; kc < 2; ++kc)
      qf[mt][kc] = *(const f16x8*)(qbase + (size_t)(mt * 16 + l15) * D + kc * 32 + quad * 8);

  f16x8 vb4;   // ones-column B-frag (n==0 lanes), for row-sum l
#pragma unroll
  for (int j = 0; j < 8; ++j) vb4[j] = (l15 == 0) ? (f16)1.0f : (f16)0.0f;

  f32x4 O[2][5];
#pragma unroll
  for (int mt = 0; mt < 2; ++mt)
#pragma unroll
    for (int nt = 0; nt < 5; ++nt) O[mt][nt] = (f32x4){0.f, 0.f, 0.f, 0.f};

  // register double-buffer for K frags
  f16x8 kf[2][2][4];
#pragma unroll
  for (int kc = 0; kc < 2; ++kc)
#pragma unroll
    for (int nt = 0; nt < 4; ++nt)
      kf[0][kc][nt] = *(const f16x8*)(kbase + (size_t)(nt * 16 + l15) * D + kc * 32 + quad * 8);

#pragma unroll 2
  for (int kt = 0; kt < S / 64; ++kt) {
    const int cur = kt & 1, nxt = cur ^ 1;

    // scores with current K frags
    f32x4 sc[2][4];
#pragma unroll
    for (int mt = 0; mt < 2; ++mt)
#pragma unroll
      for (int nt = 0; nt < 4; ++nt) sc[mt][nt] = (f32x4){0.f, 0.f, 0.f, 0.f};
#pragma unroll
    for (int kc = 0; kc < 2; ++kc)
#pragma unroll
      for (int nt = 0; nt < 4; ++nt)
#pragma unroll
        for (int mt = 0; mt < 2; ++mt)
          sc[mt][nt] = __builtin_amdgcn_mfma_f32_16x16x32_f16(qf[mt][kc], kf[cur][kc][nt], sc[mt][nt], 0, 0, 0);

    // prefetch next K tile (wraps at end; harmless)
    const int ktn = (kt + 1) & (S / 64 - 1);
#pragma unroll
    for (int kc = 0; kc < 2; ++kc)
#pragma unroll
      for (int nt = 0; nt < 4; ++nt)
        kf[nxt][kc][nt] = *(const f16x8*)(kbase + ((size_t)ktn * 64 + nt * 16 + l15) * D + kc * 32 + quad * 8);

    // V^T frags for this tile (issued before softmax VALU to hide latency)
    f16x8 vf[2][4];
#pragma unroll
    for (int kc = 0; kc < 2; ++kc)
#pragma unroll
      for (int nt = 0; nt < 4; ++nt)
        vf[kc][nt] = *(const f16x8*)(vbase + (size_t)(nt * 16 + l15) * S + kt * 64 + kc * 32 + quad * 8);

    // p = exp2(sc); pack 4 (phys p = l15*4 + nt) -> one b64 LDS write per (mt,r)
#pragma unroll
    for (int mt = 0; mt < 2; ++mt)
#pragma unroll
      for (int r = 0; r < 4; ++r) {
        const float p0 = __builtin_amdgcn_exp2f(sc[mt][0][r]);
        const float p1 = __builtin_amdgcn_exp2f(sc[mt][1][r]);
        const float p2 = __builtin_amdgcn_exp2f(sc[mt][2][r]);
        const float p3 = __builtin_amdgcn_exp2f(sc[mt][3][r]);
        union { f16x4 v4; f16x2 h[2]; } u;
        u.h[0] = __builtin_bit_cast(f16x2, __builtin_amdgcn_cvt_pkrtz(p0, p1));
        u.h[1] = __builtin_bit_cast(f16x2, __builtin_amdgcn_cvt_pkrtz(p2, p3));
        *(f16x4*)&pw[(mt * 16 + quad * 4 + r) * LP + l15 * 4] = u.v4;
      }
    __asm__ volatile("s_waitcnt lgkmcnt(0)" ::: "memory");  // own-wave P visible

    f16x8 pa[2][2];
#pragma unroll
    for (int mt = 0; mt < 2; ++mt)
#pragma unroll
      for (int kc = 0; kc < 2; ++kc)
        pa[mt][kc] = *(const f16x8*)&pw[(mt * 16 + l15) * LP + kc * 32 + quad * 8];

#pragma unroll
    for (int kc = 0; kc < 2; ++kc) {
#pragma unroll
      for (int nt = 0; nt < 4; ++nt)
#pragma unroll
        for (int mt = 0; mt < 2; ++mt)
          O[mt][nt] = __builtin_amdgcn_mfma_f32_16x16x32_f16(pa[mt][kc], vf[kc][nt], O[mt][nt], 0, 0, 0);
#pragma unroll
      for (int mt = 0; mt < 2; ++mt)
        O[mt][4] = __builtin_amdgcn_mfma_f32_16x16x32_f16(pa[mt][kc], vb4, O[mt][4], 0, 0, 0);
    }
  }

  const int b = bh >> 4, h = bh & 15;
#pragma unroll
  for (int mt = 0; mt < 2; ++mt)
#pragma unroll
    for (int r = 0; r < 4; ++r) {
      const float l = __shfl(O[mt][4][r], quad << 4, 64);
      const float inv = 1.f / l;
      const int row = q0 + w * 32 + mt * 16 + quad * 4 + r;
      f16* o = ao + ((size_t)b * S + row) * E + h * D;
#pragma unroll
      for (int nt = 0; nt < 4; ++nt)
        o[nt * 16 + l15] = (f16)(O[mt][nt][r] * inv);
    }
}

// ---------- dense: out = A·Wd^T + bd, barrier/LDS-free MFMA (frags direct from L1/L2)
__global__ __launch_bounds__(256) void dense_mfma(const f16* __restrict__ A,
                                                  const f16* __restrict__ Wd16,
                                                  const float* __restrict__ bd,
                                                  float* __restrict__ out) {
  const int t = threadIdx.x, lane = t & 63, w = t >> 6;
  const int l15 = lane & 15, quad = lane >> 4;
  const int m0 = blockIdx.x * 128, n0 = blockIdx.y * 128;
  const int wm = (w >> 1) * 64, wn = (w & 1) * 64;

  f32x4 acc[4][4];
#pragma unroll
  for (int mt = 0; mt < 4; ++mt)
#pragma unroll
    for (int nt = 0; nt < 4; ++nt) acc[mt][nt] = (f32x4){0.f, 0.f, 0.f, 0.f};

#pragma unroll
  for (int kt = 0; kt < E / 64; ++kt) {
#pragma unroll
    for (int kc = 0; kc < 2; ++kc) {
      f16x8 af[4], bf[4];
#pragma unroll
      for (int mt = 0; mt < 4; ++mt)
        af[mt] = *(const f16x8*)(A + (size_t)(m0 + wm + mt * 16 + l15) * E + kt * 64 + kc * 32 + quad * 8);
#pragma unroll
      for (int nt = 0; nt < 4; ++nt)
        bf[nt] = *(const f16x8*)(Wd16 + (size_t)(n0 + wn + nt * 16 + l15) * E + kt * 64 + kc * 32 + quad * 8);
#pragma unroll
      for (int nt = 0; nt < 4; ++nt)
#pragma unroll
        for (int mt = 0; mt < 4; ++mt)
          acc[mt][nt] = __builtin_amdgcn_mfma_f32_16x16x32_f16(af[mt], bf[nt], acc[mt][nt], 0, 0, 0);
    }
  }
#pragma unroll
  for (int nt = 0; nt < 4; ++nt) {
    const int col = n0 + wn + nt * 16 + l15;
    const float bdv = bd[col];
#pragma unroll
    for (int mt = 0; mt < 4; ++mt)
#pragma unroll
      for (int r = 0; r < 4; ++r)
        out[(size_t)(m0 + wm + mt * 16 + quad * 4 + r) * E + col] = acc[mt][nt][r] + bdv;
  }
}

extern "C" void kernel_launch(void* const* d_in, const int* in_sizes, int n_in,
                              void* d_out, int out_size, void* d_ws, size_t ws_size,
                              hipStream_t stream) {
  const float* queries = (const float*)d_in[0];
  const float* values  = (const float*)d_in[1];
  const float* Wv = (const float*)d_in[3];
  const float* bv = (const float*)d_in[4];
  const float* Wk = (const float*)d_in[5];
  const float* bk = (const float*)d_in[6];
  const float* Wq = (const float*)d_in[7];
  const float* bq = (const float*)d_in[8];
  const float* Wd = (const float*)d_in[9];
  const float* bd = (const float*)d_in[10];
  float* out = (float*)d_out;

  char* ws = (char*)d_ws;
  f16* qp    = (f16*)(ws);                          // 8 MB [B,H,S,D]  (pre-scaled by QSCALE)
  f16* kp    = (f16*)(ws + 8u * 1024 * 1024);       // 8 MB [B,H,S,D]
  f16* vp    = (f16*)(ws + 16u * 1024 * 1024);      // 8 MB [B,H,S,D]
  f16* ao    = (f16*)(ws + 24u * 1024 * 1024);      // 8 MB [B,S,E]
  f16* wd16  = (f16*)(ws + 32u * 1024 * 1024);      // 2 MB
  float* wkv = (float*)(ws + 34u * 1024 * 1024);    // 16 KB
  float* bkv = (float*)(ws + 34u * 1024 * 1024 + 16384);
  f16* vtg   = (f16*)(ws + 36u * 1024 * 1024);      // 8 MB [B,H,D,S] (kv-permuted per 64-tile)
  (void)ws_size; (void)in_sizes; (void)n_in; (void)out_size;

  make_wkv<<<16, 256, 0, stream>>>(Wk, Wv, bv, bk, wkv, bkv);
  cvt_wd<<<E * E / 1024, 256, 0, stream>>>(Wd, wd16);
  proj_mfma<<<256, 256, 0, stream>>>(queries, Wq, bq, qp, QSCALE);
  proj_vk_mfma<<<512, 256, 0, stream>>>(values, Wv, bv, wkv, bkv, vp, kp);
  transpose_v<<<dim3(B * H, S / 64), 256, 0, stream>>>(vp, vtg);
  attn_mfma<<<dim3(B * H, S / 128), 256, 0, stream>>>(qp, kp, vtg, ao);
  dense_mfma<<<dim3(B * S / 128, E / 128), 256, 0, stream>>>(ao, wd16, bd, out);
}

// Round 6
// 219.415 us; speedup vs baseline: 1.2513x; 1.2513x over previous
//
#include <hip/hip_runtime.h>
#include <hip/hip_bf16.h>
#include <hip/hip_fp16.h>
#include <math.h>

typedef _Float16 f16;
typedef _Float16 f16x8 __attribute__((ext_vector_type(8)));
typedef _Float16 f16x4 __attribute__((ext_vector_type(4)));
typedef _Float16 f16x2 __attribute__((ext_vector_type(2)));
typedef unsigned short u16x8v __attribute__((ext_vector_type(8)));
typedef float f32x4 __attribute__((ext_vector_type(4)));

namespace {
constexpr int B = 2;
constexpr int H = 16;
constexpr int S = 2048;
constexpr int D = 64;
constexpr int E = 1024;
constexpr int LP = 72;   // LDS row stride (f16)
constexpr int NSPLIT = 2;  // kv splits in attention
constexpr float QSCALE = 0.125f * 1.4426950408889634f;  // 1/sqrt(64) * log2(e)
}

// ---------- Wkv = Wk*Wv, bkv = Wk*bv + bk  (fp32, tiny)
__global__ void make_wkv(const float* __restrict__ Wk, const float* __restrict__ Wv,
                         const float* __restrict__ bv, const float* __restrict__ bk,
                         float* __restrict__ Wkv, float* __restrict__ bkv) {
  const int g = blockIdx.x * 256 + threadIdx.x;   // 0..4095
  const int i = g >> 6, j = g & 63;
  float s = 0.f;
#pragma unroll 16
  for (int d = 0; d < 64; ++d) s = fmaf(Wk[i * 64 + d], Wv[d * 64 + j], s);
  Wkv[g] = s;
  if (g < 64) {
    float bb = bk[g];
#pragma unroll 16
    for (int d = 0; d < 64; ++d) bb = fmaf(Wk[g * 64 + d], bv[d], bb);
    bkv[g] = bb;
  }
}

// ---------- q projection: one-shot MFMA GEMM (M=65536, K=64, N=64), scale folded
__global__ __launch_bounds__(256) void proj_mfma(const float* __restrict__ x,
                                                 const float* __restrict__ W,
                                                 const float* __restrict__ bias,
                                                 f16* __restrict__ out, float scale) {
  const int t = threadIdx.x, lane = t & 63, w = t >> 6;
  const int l15 = lane & 15, quad = lane >> 4;
  const int m0 = (blockIdx.x * 4 + w) * 64;

  f16x8 wf[4][2], af[4][2];
#pragma unroll
  for (int nt = 0; nt < 4; ++nt)
#pragma unroll
    for (int kc = 0; kc < 2; ++kc) {
      const float* g = W + (size_t)(nt * 16 + l15) * 64 + kc * 32 + quad * 8;
      const float4 a = *(const float4*)g, b2 = *(const float4*)(g + 4);
      f16x8 v;
      v[0]=(f16)a.x; v[1]=(f16)a.y; v[2]=(f16)a.z; v[3]=(f16)a.w;
      v[4]=(f16)b2.x; v[5]=(f16)b2.y; v[6]=(f16)b2.z; v[7]=(f16)b2.w;
      wf[nt][kc] = v;
    }
#pragma unroll
  for (int mt = 0; mt < 4; ++mt)
#pragma unroll
    for (int kc = 0; kc < 2; ++kc) {
      const float* g = x + (size_t)(m0 + mt * 16 + l15) * 64 + kc * 32 + quad * 8;
      const float4 a = *(const float4*)g, b2 = *(const float4*)(g + 4);
      f16x8 v;
      v[0]=(f16)a.x; v[1]=(f16)a.y; v[2]=(f16)a.z; v[3]=(f16)a.w;
      v[4]=(f16)b2.x; v[5]=(f16)b2.y; v[6]=(f16)b2.z; v[7]=(f16)b2.w;
      af[mt][kc] = v;
    }

  f32x4 acc[4][4];
#pragma unroll
  for (int mt = 0; mt < 4; ++mt)
#pragma unroll
    for (int nt = 0; nt < 4; ++nt) acc[mt][nt] = (f32x4){0.f, 0.f, 0.f, 0.f};
#pragma unroll
  for (int kc = 0; kc < 2; ++kc)
#pragma unroll
    for (int nt = 0; nt < 4; ++nt)
#pragma unroll
      for (int mt = 0; mt < 4; ++mt)
        acc[mt][nt] = __builtin_amdgcn_mfma_f32_16x16x32_f16(af[mt][kc], wf[nt][kc], acc[mt][nt], 0, 0, 0);

  float bl[4];
#pragma unroll
  for (int nt = 0; nt < 4; ++nt) bl[nt] = bias[nt * 16 + l15];

#pragma unroll
  for (int mt = 0; mt < 4; ++mt)
#pragma unroll
    for (int r = 0; r < 4; ++r) {
      const int g = m0 + mt * 16 + quad * 4 + r;   // (b*S+s)*H + h
      const int h = g & 15, bs = g >> 4;
      const int b = bs >> 11, s = bs & 2047;
      f16* o = out + ((size_t)(b * H + h) * S + s) * 64;
#pragma unroll
      for (int nt = 0; nt < 4; ++nt)
        o[nt * 16 + l15] = (f16)((acc[mt][nt][r] + bl[nt]) * scale);
    }
}

// ---------- fused v & k projections sharing A-frags (k = x·Wkv^T + bkv == quirk)
__global__ __launch_bounds__(256) void proj_vk_mfma(const float* __restrict__ x,
                                                    const float* __restrict__ Wv,
                                                    const float* __restrict__ bv,
                                                    const float* __restrict__ Wkv,
                                                    const float* __restrict__ bkv,
                                                    f16* __restrict__ vout,
                                                    f16* __restrict__ kout) {
  const int t = threadIdx.x, lane = t & 63, w = t >> 6;
  const int l15 = lane & 15, quad = lane >> 4;
  const int m0 = (blockIdx.x * 4 + w) * 32;

  f16x8 wfv[4][2], wfk[4][2], af[2][2];
#pragma unroll
  for (int nt = 0; nt < 4; ++nt)
#pragma unroll
    for (int kc = 0; kc < 2; ++kc) {
      const size_t off = (size_t)(nt * 16 + l15) * 64 + kc * 32 + quad * 8;
      {
        const float4 a = *(const float4*)(Wv + off), b2 = *(const float4*)(Wv + off + 4);
        f16x8 v;
        v[0]=(f16)a.x; v[1]=(f16)a.y; v[2]=(f16)a.z; v[3]=(f16)a.w;
        v[4]=(f16)b2.x; v[5]=(f16)b2.y; v[6]=(f16)b2.z; v[7]=(f16)b2.w;
        wfv[nt][kc] = v;
      }
      {
        const float4 a = *(const float4*)(Wkv + off), b2 = *(const float4*)(Wkv + off + 4);
        f16x8 v;
        v[0]=(f16)a.x; v[1]=(f16)a.y; v[2]=(f16)a.z; v[3]=(f16)a.w;
        v[4]=(f16)b2.x; v[5]=(f16)b2.y; v[6]=(f16)b2.z; v[7]=(f16)b2.w;
        wfk[nt][kc] = v;
      }
    }
#pragma unroll
  for (int mt = 0; mt < 2; ++mt)
#pragma unroll
    for (int kc = 0; kc < 2; ++kc) {
      const float* g = x + (size_t)(m0 + mt * 16 + l15) * 64 + kc * 32 + quad * 8;
      const float4 a = *(const float4*)g, b2 = *(const float4*)(g + 4);
      f16x8 v;
      v[0]=(f16)a.x; v[1]=(f16)a.y; v[2]=(f16)a.z; v[3]=(f16)a.w;
      v[4]=(f16)b2.x; v[5]=(f16)b2.y; v[6]=(f16)b2.z; v[7]=(f16)b2.w;
      af[mt][kc] = v;
    }

  f32x4 accv[2][4], acck[2][4];
#pragma unroll
  for (int mt = 0; mt < 2; ++mt)
#pragma unroll
    for (int nt = 0; nt < 4; ++nt) {
      accv[mt][nt] = (f32x4){0.f, 0.f, 0.f, 0.f};
      acck[mt][nt] = (f32x4){0.f, 0.f, 0.f, 0.f};
    }
#pragma unroll
  for (int kc = 0; kc < 2; ++kc)
#pragma unroll
    for (int nt = 0; nt < 4; ++nt)
#pragma unroll
      for (int mt = 0; mt < 2; ++mt) {
        accv[mt][nt] = __builtin_amdgcn_mfma_f32_16x16x32_f16(af[mt][kc], wfv[nt][kc], accv[mt][nt], 0, 0, 0);
        acck[mt][nt] = __builtin_amdgcn_mfma_f32_16x16x32_f16(af[mt][kc], wfk[nt][kc], acck[mt][nt], 0, 0, 0);
      }

  float blv[4], blk[4];
#pragma unroll
  for (int nt = 0; nt < 4; ++nt) { blv[nt] = bv[nt * 16 + l15]; blk[nt] = bkv[nt * 16 + l15]; }

#pragma unroll
  for (int mt = 0; mt < 2; ++mt)
#pragma unroll
    for (int r = 0; r < 4; ++r) {
      const int g = m0 + mt * 16 + quad * 4 + r;
      const int h = g & 15, bs = g >> 4;
      const int b = bs >> 11, s = bs & 2047;
      const size_t o = ((size_t)(b * H + h) * S + s) * 64;
#pragma unroll
      for (int nt = 0; nt < 4; ++nt) {
        vout[o + nt * 16 + l15] = (f16)(accv[mt][nt][r] + blv[nt]);
        kout[o + nt * 16 + l15] = (f16)(acck[mt][nt][r] + blk[nt]);
      }
    }
}

// ---------- MFMA flash attention with kv-split. R4 LDS-staged structure.
// grid (B*H, S/128, NSPLIT); each block does 1024/64=16 kv tiles.
// Writes UNNORMALIZED fp32 partial O + l per split.
__global__ __launch_bounds__(256) void attn_mfma(const f16* __restrict__ qp,
                                                 const f16* __restrict__ kp,
                                                 const f16* __restrict__ vp,
                                                 float* __restrict__ part0,
                                                 float* __restrict__ part1,
                                                 float* __restrict__ lp0,
                                                 float* __restrict__ lp1) {
  __shared__ f16 ks[64 * LP];       // K tile [kv][d]
  __shared__ f16 vt[64 * LP];       // V^T tile [d][p], kv(p) = (p&3)*16 + (p>>2)
  __shared__ f16 ps[4 * 32 * LP];   // per-wave P [32 q][p]
  const int t = threadIdx.x, lane = t & 63, w = t >> 6;
  const int l15 = lane & 15, quad = lane >> 4;
  const int bh = blockIdx.x;
  const int q0 = blockIdx.y * 128;
  const int split = blockIdx.z;
  const f16* qbase = qp + ((size_t)bh * S + q0 + w * 32) * D;
  const f16* kbase = kp + (size_t)bh * S * D;
  const f16* vbase = vp + (size_t)bh * S * D;
  f16* pw = ps + w * 32 * LP;

  f16x8 qf[2][2];
#pragma unroll
  for (int mt = 0; mt < 2; ++mt)
#pragma unroll
    for (int kc = 0; kc < 2; ++kc)
      qf[mt][kc] = *(const f16x8*)(qbase + (size_t)(mt * 16 + l15) * D + kc * 32 + quad * 8);

  f16x8 vb4;   // ones-column B-frag (n==0), row-sum l accumulator feed
#pragma unroll
  for (int j = 0; j < 8; ++j) vb4[j] = (l15 == 0) ? (f16)1.0f : (f16)0.0f;

  f32x4 O[2][5];
#pragma unroll
  for (int mt = 0; mt < 2; ++mt)
#pragma unroll
    for (int nt = 0; nt < 5; ++nt) O[mt][nt] = (f32x4){0.f, 0.f, 0.f, 0.f};

  const int kt0 = split * (S / 64 / NSPLIT);
  const int kt1 = kt0 + (S / 64 / NSPLIT);
  for (int kt = kt0; kt < kt1; ++kt) {
    __syncthreads();
    {  // K stage row-major
      const int r = t >> 2, c0 = (t & 3) * 16;
      const f16* g = kbase + ((size_t)kt * 64 + r) * D + c0;
      *(f16x8*)&ks[r * LP + c0] = *(const f16x8*)g;
      *(f16x8*)&ks[r * LP + c0 + 8] = *(const f16x8*)(g + 8);
    }
    {  // V stage transposed + kv-permuted
      const int d0 = (t >> 5) * 8, pc0 = (t & 31) * 2;
      const int kva = (pc0 & 3) * 16 + (pc0 >> 2);
      const u16x8v a = *(const u16x8v*)(vbase + ((size_t)kt * 64 + kva) * D + d0);
      const u16x8v b2 = *(const u16x8v*)(vbase + ((size_t)kt * 64 + kva + 16) * D + d0);
#pragma unroll
      for (int j = 0; j < 8; ++j) {
        const unsigned pk = (unsigned)a[j] | ((unsigned)b2[j] << 16);
        *(unsigned*)&vt[(d0 + j) * LP + pc0] = pk;
      }
    }
    __syncthreads();

    // scores (Q pre-scaled): col n = kv nt*16+l15
    f32x4 sc[2][4];
#pragma unroll
    for (int mt = 0; mt < 2; ++mt)
#pragma unroll
      for (int nt = 0; nt < 4; ++nt) sc[mt][nt] = (f32x4){0.f, 0.f, 0.f, 0.f};
#pragma unroll
    for (int kc = 0; kc < 2; ++kc)
#pragma unroll
      for (int nt = 0; nt < 4; ++nt) {
        const f16x8 bf = *(const f16x8*)&ks[(nt * 16 + l15) * LP + kc * 32 + quad * 8];
#pragma unroll
        for (int mt = 0; mt < 2; ++mt)
          sc[mt][nt] = __builtin_amdgcn_mfma_f32_16x16x32_f16(qf[mt][kc], bf, sc[mt][nt], 0, 0, 0);
      }

    // p = exp2(sc); phys col = l15*4 + nt -> one b64 write per (mt,r)
#pragma unroll
    for (int mt = 0; mt < 2; ++mt)
#pragma unroll
      for (int r = 0; r < 4; ++r) {
        const float p0 = __builtin_amdgcn_exp2f(sc[mt][0][r]);
        const float p1 = __builtin_amdgcn_exp2f(sc[mt][1][r]);
        const float p2 = __builtin_amdgcn_exp2f(sc[mt][2][r]);
        const float p3 = __builtin_amdgcn_exp2f(sc[mt][3][r]);
        union { f16x4 v4; f16x2 h[2]; } u;
        u.h[0] = __builtin_bit_cast(f16x2, __builtin_amdgcn_cvt_pkrtz(p0, p1));
        u.h[1] = __builtin_bit_cast(f16x2, __builtin_amdgcn_cvt_pkrtz(p2, p3));
        *(f16x4*)&pw[(mt * 16 + quad * 4 + r) * LP + l15 * 4] = u.v4;
      }
    __asm__ volatile("s_waitcnt lgkmcnt(0)" ::: "memory");  // own-wave P visible

    f16x8 pa[2][2];
#pragma unroll
    for (int mt = 0; mt < 2; ++mt)
#pragma unroll
      for (int kc = 0; kc < 2; ++kc)
        pa[mt][kc] = *(const f16x8*)&pw[(mt * 16 + l15) * LP + kc * 32 + quad * 8];

#pragma unroll
    for (int kc = 0; kc < 2; ++kc) {
#pragma unroll
      for (int nt = 0; nt < 4; ++nt) {
        const f16x8 vbf = *(const f16x8*)&vt[(nt * 16 + l15) * LP + kc * 32 + quad * 8];
#pragma unroll
        for (int mt = 0; mt < 2; ++mt)
          O[mt][nt] = __builtin_amdgcn_mfma_f32_16x16x32_f16(pa[mt][kc], vbf, O[mt][nt], 0, 0, 0);
      }
#pragma unroll
      for (int mt = 0; mt < 2; ++mt)
        O[mt][4] = __builtin_amdgcn_mfma_f32_16x16x32_f16(pa[mt][kc], vb4, O[mt][4], 0, 0, 0);
    }
  }

  // epilogue: UNNORMALIZED fp32 partial + l  (partial layout: [(bh*S + q)][d])
  float* Opart = split ? part1 : part0;
  float* Lpart = split ? lp1 : lp0;
#pragma unroll
  for (int mt = 0; mt < 2; ++mt)
#pragma unroll
    for (int r = 0; r < 4; ++r) {
      const float l = __shfl(O[mt][4][r], quad << 4, 64);
      const int row = q0 + w * 32 + mt * 16 + quad * 4 + r;
      float* o = Opart + ((size_t)bh * S + row) * 64;
#pragma unroll
      for (int nt = 0; nt < 4; ++nt)
        o[nt * 16 + l15] = O[mt][nt][r];
      if (l15 == 0) Lpart[(size_t)bh * S + row] = l;
    }
}

// ---------- combine splits: ao = (P0+P1)/(l0+l1), f16 [B,S,E]
__global__ __launch_bounds__(256) void combine_attn(const float* __restrict__ p0,
                                                    const float* __restrict__ p1,
                                                    const float* __restrict__ l0,
                                                    const float* __restrict__ l1,
                                                    f16* __restrict__ ao) {
  const int i = blockIdx.x * 256 + threadIdx.x;   // x4 floats
  const size_t e0 = (size_t)i * 4;
  const int row = (int)(e0 >> 6);     // bh*S + q
  const int d = (int)(e0 & 63);
  const float inv = 1.f / (l0[row] + l1[row]);
  const float4 a = *(const float4*)(p0 + e0);
  const float4 b2 = *(const float4*)(p1 + e0);
  const int bh = row >> 11, q = row & 2047;
  const int b = bh >> 4, h = bh & 15;
  f16x4 o;
  o.x = (f16)((a.x + b2.x) * inv);
  o.y = (f16)((a.y + b2.y) * inv);
  o.z = (f16)((a.z + b2.z) * inv);
  o.w = (f16)((a.w + b2.w) * inv);
  *(f16x4*)(ao + ((size_t)b * S + q) * E + h * 64 + d) = o;
}

// ---------- dense: out = A·Wd^T + bd (LDS-staged MFMA; Wd converted fp32->f16 in staging)
__global__ __launch_bounds__(256) void dense_mfma(const f16* __restrict__ A,
                                                  const float* __restrict__ Wd,
                                                  const float* __restrict__ bd,
                                                  float* __restrict__ out) {
  __shared__ f16 as[128 * LP];
  __shared__ f16 bs[128 * LP];
  const int t = threadIdx.x;
  const int lane = t & 63;
  const int w = t >> 6;
  const int l15 = lane & 15;
  const int quad = lane >> 4;
  const int m0 = blockIdx.x * 128;
  const int n0 = blockIdx.y * 128;
  const int wm = (w >> 1) * 64, wn = (w & 1) * 64;

  f32x4 acc[4][4];
#pragma unroll
  for (int mt = 0; mt < 4; ++mt)
#pragma unroll
    for (int nt = 0; nt < 4; ++nt) acc[mt][nt] = (f32x4){0.f, 0.f, 0.f, 0.f};

  for (int kt = 0; kt < E / 64; ++kt) {
    __syncthreads();
    {
      const int r = t >> 1, c0 = (t & 1) * 32;
      const f16* ga = A + (size_t)(m0 + r) * E + kt * 64 + c0;
      const float* gb = Wd + (size_t)(n0 + r) * E + kt * 64 + c0;
#pragma unroll
      for (int c = 0; c < 4; ++c)
        *(f16x8*)&as[r * LP + c0 + 8 * c] = *(const f16x8*)(ga + 8 * c);
#pragma unroll
      for (int c = 0; c < 4; ++c) {
        const float4 a = *(const float4*)(gb + 8 * c), b2 = *(const float4*)(gb + 8 * c + 4);
        f16x8 v;
        v[0]=(f16)a.x; v[1]=(f16)a.y; v[2]=(f16)a.z; v[3]=(f16)a.w;
        v[4]=(f16)b2.x; v[5]=(f16)b2.y; v[6]=(f16)b2.z; v[7]=(f16)b2.w;
        *(f16x8*)&bs[r * LP + c0 + 8 * c] = v;
      }
    }
    __syncthreads();
    f16x8 af[4][2];
#pragma unroll
    for (int mt = 0; mt < 4; ++mt)
#pragma unroll
      for (int kc = 0; kc < 2; ++kc)
        af[mt][kc] = *(const f16x8*)&as[(wm + mt * 16 + l15) * LP + kc * 32 + quad * 8];
#pragma unroll
    for (int kc = 0; kc < 2; ++kc)
#pragma unroll
      for (int nt = 0; nt < 4; ++nt) {
        const f16x8 bf = *(const f16x8*)&bs[(wn + nt * 16 + l15) * LP + kc * 32 + quad * 8];
#pragma unroll
        for (int mt = 0; mt < 4; ++mt)
          acc[mt][nt] = __builtin_amdgcn_mfma_f32_16x16x32_f16(af[mt][kc], bf, acc[mt][nt], 0, 0, 0);
      }
  }
#pragma unroll
  for (int nt = 0; nt < 4; ++nt) {
    const int col = n0 + wn + nt * 16 + l15;
    const float bdv = bd[col];
#pragma unroll
    for (int mt = 0; mt < 4; ++mt)
#pragma unroll
      for (int r = 0; r < 4; ++r)
        out[(size_t)(m0 + wm + mt * 16 + quad * 4 + r) * E + col] = acc[mt][nt][r] + bdv;
  }
}

extern "C" void kernel_launch(void* const* d_in, const int* in_sizes, int n_in,
                              void* d_out, int out_size, void* d_ws, size_t ws_size,
                              hipStream_t stream) {
  const float* queries = (const float*)d_in[0];
  const float* values  = (const float*)d_in[1];
  const float* Wv = (const float*)d_in[3];
  const float* bv = (const float*)d_in[4];
  const float* Wk = (const float*)d_in[5];
  const float* bk = (const float*)d_in[6];
  const float* Wq = (const float*)d_in[7];
  const float* bq = (const float*)d_in[8];
  const float* Wd = (const float*)d_in[9];
  const float* bd = (const float*)d_in[10];
  float* out = (float*)d_out;

  char* ws = (char*)d_ws;
  f16* qp    = (f16*)(ws);                          // 8 MB [B,H,S,D] (pre-scaled by QSCALE)
  f16* kp    = (f16*)(ws + 8u * 1024 * 1024);       // 8 MB
  f16* vp    = (f16*)(ws + 16u * 1024 * 1024);      // 8 MB
  f16* ao    = (f16*)(ws + 24u * 1024 * 1024);      // 8 MB [B,S,E]
  float* wkv = (float*)(ws + 32u * 1024 * 1024);    // 16 KB
  float* bkv = (float*)(ws + 32u * 1024 * 1024 + 16384);
  float* lp0 = (float*)(ws + 33u * 1024 * 1024);    // 256 KB  [B*H*S]
  float* lp1 = (float*)(ws + 33u * 1024 * 1024 + 256 * 1024);
  float* p0  = (float*)(ws + 34u * 1024 * 1024);    // 16 MB fp32 partial (split 0)
  float* p1  = out;                                 // split-1 partial borrows d_out (16 MB)
  (void)ws_size; (void)in_sizes; (void)n_in; (void)out_size;

  make_wkv<<<16, 256, 0, stream>>>(Wk, Wv, bv, bk, wkv, bkv);
  proj_mfma<<<256, 256, 0, stream>>>(queries, Wq, bq, qp, QSCALE);
  proj_vk_mfma<<<512, 256, 0, stream>>>(values, Wv, bv, wkv, bkv, vp, kp);
  attn_mfma<<<dim3(B * H, S / 128, NSPLIT), 256, 0, stream>>>(qp, kp, vp, p0, p1, lp0, lp1);
  combine_attn<<<B * H * S * D / (4 * 256), 256, 0, stream>>>(p0, p1, lp0, lp1, ao);
  dense_mfma<<<dim3(B * S / 128, E / 128), 256, 0, stream>>>(ao, Wd, bd, out);
}

// Round 8
// 201.192 us; speedup vs baseline: 1.3647x; 1.0906x over previous
//
#include <hip/hip_runtime.h>
#include <hip/hip_bf16.h>
#include <hip/hip_fp16.h>
#include <math.h>

typedef _Float16 f16;
typedef _Float16 f16x8 __attribute__((ext_vector_type(8)));
typedef _Float16 f16x4 __attribute__((ext_vector_type(4)));
typedef _Float16 f16x2 __attribute__((ext_vector_type(2)));
typedef float f32x4 __attribute__((ext_vector_type(4)));

// legacy CDNA spelling (gfx908+, still valid on gfx950): v_mfma_f32_16x16x16_f16
#define MFMA16(a, b, c) __builtin_amdgcn_mfma_f32_16x16x16f16((a), (b), (c), 0, 0, 0)
#define MFMA32(a, b, c) __builtin_amdgcn_mfma_f32_16x16x32_f16((a), (b), (c), 0, 0, 0)

namespace {
constexpr int B = 2;
constexpr int H = 16;
constexpr int S = 2048;
constexpr int D = 64;
constexpr int E = 1024;
constexpr int LP = 72;   // LDS row stride (f16)
constexpr float QSCALE = 0.125f * 1.4426950408889634f;  // 1/sqrt(64) * log2(e)
}

__device__ __forceinline__ f16x4 cvt4(float a, float b, float c, float d) {
  union { f16x4 v4; f16x2 h[2]; } u;
  u.h[0] = __builtin_bit_cast(f16x2, __builtin_amdgcn_cvt_pkrtz(a, b));
  u.h[1] = __builtin_bit_cast(f16x2, __builtin_amdgcn_cvt_pkrtz(c, d));
  return u.v4;
}

// ---------- q projection (x32 MFMA GEMM), QSCALE folded; out qp[b,h,s,d] f16
__global__ __launch_bounds__(256) void proj_q(const float* __restrict__ x,
                                              const float* __restrict__ W,
                                              const float* __restrict__ bias,
                                              f16* __restrict__ out) {
  const int t = threadIdx.x, lane = t & 63, w = t >> 6;
  const int l15 = lane & 15, quad = lane >> 4;
  const int m0 = (blockIdx.x * 4 + w) * 32;

  f16x8 wf[4][2], af[2][2];
#pragma unroll
  for (int nt = 0; nt < 4; ++nt)
#pragma unroll
    for (int kc = 0; kc < 2; ++kc) {
      const float* g = W + (size_t)(nt * 16 + l15) * 64 + kc * 32 + quad * 8;
      const float4 a = *(const float4*)g, b2 = *(const float4*)(g + 4);
      f16x8 v;
      v[0]=(f16)a.x; v[1]=(f16)a.y; v[2]=(f16)a.z; v[3]=(f16)a.w;
      v[4]=(f16)b2.x; v[5]=(f16)b2.y; v[6]=(f16)b2.z; v[7]=(f16)b2.w;
      wf[nt][kc] = v;
    }
#pragma unroll
  for (int mt = 0; mt < 2; ++mt)
#pragma unroll
    for (int kc = 0; kc < 2; ++kc) {
      const float* g = x + (size_t)(m0 + mt * 16 + l15) * 64 + kc * 32 + quad * 8;
      const float4 a = *(const float4*)g, b2 = *(const float4*)(g + 4);
      f16x8 v;
      v[0]=(f16)a.x; v[1]=(f16)a.y; v[2]=(f16)a.z; v[3]=(f16)a.w;
      v[4]=(f16)b2.x; v[5]=(f16)b2.y; v[6]=(f16)b2.z; v[7]=(f16)b2.w;
      af[mt][kc] = v;
    }

  f32x4 acc[2][4];
#pragma unroll
  for (int mt = 0; mt < 2; ++mt)
#pragma unroll
    for (int nt = 0; nt < 4; ++nt) acc[mt][nt] = (f32x4){0.f, 0.f, 0.f, 0.f};
#pragma unroll
  for (int kc = 0; kc < 2; ++kc)
#pragma unroll
    for (int nt = 0; nt < 4; ++nt)
#pragma unroll
      for (int mt = 0; mt < 2; ++mt)
        acc[mt][nt] = MFMA32(af[mt][kc], wf[nt][kc], acc[mt][nt]);

  float bl[4];
#pragma unroll
  for (int nt = 0; nt < 4; ++nt) bl[nt] = bias[nt * 16 + l15];

#pragma unroll
  for (int mt = 0; mt < 2; ++mt)
#pragma unroll
    for (int r = 0; r < 4; ++r) {
      const int g = m0 + mt * 16 + quad * 4 + r;   // (b*S+s)*H + h
      const int h = g & 15, bs = g >> 4;
      const int b = bs >> 11, s = bs & 2047;
      f16* o = out + ((size_t)(b * H + h) * S + s) * 64;
#pragma unroll
      for (int nt = 0; nt < 4; ++nt)
        o[nt * 16 + l15] = (f16)((acc[mt][nt][r] + bl[nt]) * QSCALE);
    }
}

// ---------- fused v & k projections via chained x16 MFMA (k from the f16 projected v
// == reference quirk). Outputs: vtg[b,h][e][s] f16 (V transposed), kp[b,h][s][e] f16.
__global__ __launch_bounds__(256) void proj_vk(const float* __restrict__ x,
                                               const float* __restrict__ Wv,
                                               const float* __restrict__ bv,
                                               const float* __restrict__ Wk,
                                               const float* __restrict__ bk,
                                               f16* __restrict__ vtg,
                                               f16* __restrict__ kp) {
  const int t = threadIdx.x, lane = t & 63, w = t >> 6;
  const int l15 = lane & 15, quad = lane >> 4;
  const int bh = blockIdx.x;
  const int b = bh >> 4, h = bh & 15;
  const int s0 = blockIdx.y * 128 + w * 32;

  // x^T B-frags: (k=d=quad*4+i, n=token=l15)
  f16x4 xb[2][4];
#pragma unroll
  for (int nt = 0; nt < 2; ++nt)
#pragma unroll
    for (int kc = 0; kc < 4; ++kc) {
      const float4 f = *(const float4*)(x + ((size_t)(b * S + s0 + nt * 16 + l15)) * E + h * 64 + kc * 16 + quad * 4);
      f16x4 v; v[0]=(f16)f.x; v[1]=(f16)f.y; v[2]=(f16)f.z; v[3]=(f16)f.w;
      xb[nt][kc] = v;
    }

  // v^T = Wv · x^T
  f32x4 av[4][2];
#pragma unroll
  for (int mt = 0; mt < 4; ++mt)
#pragma unroll
    for (int nt = 0; nt < 2; ++nt) av[mt][nt] = (f32x4){0.f, 0.f, 0.f, 0.f};
#pragma unroll
  for (int kc = 0; kc < 4; ++kc) {
    f16x4 wvf[4];
#pragma unroll
    for (int mt = 0; mt < 4; ++mt) {
      const float4 f = *(const float4*)(Wv + (size_t)(mt * 16 + l15) * 64 + kc * 16 + quad * 4);
      f16x4 v; v[0]=(f16)f.x; v[1]=(f16)f.y; v[2]=(f16)f.z; v[3]=(f16)f.w;
      wvf[mt] = v;
    }
#pragma unroll
    for (int mt = 0; mt < 4; ++mt)
#pragma unroll
      for (int nt = 0; nt < 2; ++nt)
        av[mt][nt] = MFMA16(wvf[mt], xb[nt][kc], av[mt][nt]);
  }

  // bias, store v^T, pack as B-frags for k-chain (C-layout == B-layout for x16)
  f16x4 vB[4][2];
#pragma unroll
  for (int mt = 0; mt < 4; ++mt) {
    const float4 bb = *(const float4*)(bv + mt * 16 + quad * 4);
#pragma unroll
    for (int nt = 0; nt < 2; ++nt) {
      const float v0 = av[mt][nt][0] + bb.x;
      const float v1 = av[mt][nt][1] + bb.y;
      const float v2 = av[mt][nt][2] + bb.z;
      const float v3 = av[mt][nt][3] + bb.w;
      const f16x4 pk = cvt4(v0, v1, v2, v3);
      vB[mt][nt] = pk;
      const int sc = s0 + nt * 16 + l15;
      f16* vo = vtg + ((size_t)bh * 64 + mt * 16 + quad * 4) * S + sc;
      vo[0 * S] = pk[0]; vo[1 * S] = pk[1]; vo[2 * S] = pk[2]; vo[3 * S] = pk[3];
    }
  }

  // k^T = Wk · v^T  (v already f16 — matches what attention consumes)
  f32x4 ak[4][2];
#pragma unroll
  for (int mt = 0; mt < 4; ++mt)
#pragma unroll
    for (int nt = 0; nt < 2; ++nt) ak[mt][nt] = (f32x4){0.f, 0.f, 0.f, 0.f};
#pragma unroll
  for (int ch = 0; ch < 4; ++ch) {
    f16x4 wkf[4];
#pragma unroll
    for (int mt = 0; mt < 4; ++mt) {
      const float4 f = *(const float4*)(Wk + (size_t)(mt * 16 + l15) * 64 + ch * 16 + quad * 4);
      f16x4 v; v[0]=(f16)f.x; v[1]=(f16)f.y; v[2]=(f16)f.z; v[3]=(f16)f.w;
      wkf[mt] = v;
    }
#pragma unroll
    for (int mt = 0; mt < 4; ++mt)
#pragma unroll
      for (int nt = 0; nt < 2; ++nt)
        ak[mt][nt] = MFMA16(wkf[mt], vB[ch][nt], ak[mt][nt]);
  }
#pragma unroll
  for (int mt = 0; mt < 4; ++mt) {
    const float4 bb = *(const float4*)(bk + mt * 16 + quad * 4);
#pragma unroll
    for (int nt = 0; nt < 2; ++nt) {
      const int sc = s0 + nt * 16 + l15;
      const f16x4 pk = cvt4(ak[mt][nt][0] + bb.x, ak[mt][nt][1] + bb.y,
                            ak[mt][nt][2] + bb.z, ak[mt][nt][3] + bb.w);
      *(f16x4*)(kp + ((size_t)bh * S + sc) * 64 + mt * 16 + quad * 4) = pk;
    }
  }
}

// ---------- attention: S^T = K·Q^T (x16), exp2 in registers feeds PV B-frags directly.
// qp[b,h,s,d] (pre-scaled), kp[b,h,s,d], vtg[b,h,d,s]; ao[b,s,e] f16.
__global__ __launch_bounds__(256) void attn_mfma(const f16* __restrict__ qp,
                                                 const f16* __restrict__ kp,
                                                 const f16* __restrict__ vtg,
                                                 f16* __restrict__ ao) {
  __shared__ f16 ks[64 * LP];   // K tile [kv][d]
  __shared__ f16 vt[64 * LP];   // V^T tile [d][kv]
  const int t = threadIdx.x, lane = t & 63, w = t >> 6;
  const int l15 = lane & 15, quad = lane >> 4;
  const int bh = blockIdx.x;
  const int q0 = blockIdx.y * 128;
  const f16* qbase = qp + ((size_t)bh * S + q0 + w * 32) * D;
  const f16* kbase = kp + (size_t)bh * S * D;
  const f16* vbase = vtg + (size_t)bh * 64 * S;

  // Q^T B-frags: (k=d=quad*4+i, n=q=l15)
  f16x4 qf[2][4];
#pragma unroll
  for (int nt = 0; nt < 2; ++nt)
#pragma unroll
    for (int kc = 0; kc < 4; ++kc)
      qf[nt][kc] = *(const f16x4*)(qbase + (size_t)(nt * 16 + l15) * D + kc * 16 + quad * 4);

  f32x4 Ot[4][2];   // O^T accum: (row=d=dt*16+quad*4+r, col=q=l15)
#pragma unroll
  for (int dt = 0; dt < 4; ++dt)
#pragma unroll
    for (int nt = 0; nt < 2; ++nt) Ot[dt][nt] = (f32x4){0.f, 0.f, 0.f, 0.f};
  float lsum[2] = {0.f, 0.f};

  for (int kt = 0; kt < S / 64; ++kt) {
    __syncthreads();
    {  // stage K tile rows
      const int r = t >> 2, c0 = (t & 3) * 16;
      const f16* g = kbase + ((size_t)kt * 64 + r) * D + c0;
      *(f16x8*)&ks[r * LP + c0] = *(const f16x8*)g;
      *(f16x8*)&ks[r * LP + c0 + 8] = *(const f16x8*)(g + 8);
    }
    {  // stage V^T tile rows (already transposed in global)
      const int r = t >> 2, c0 = (t & 3) * 16;
      const f16* g = vbase + (size_t)r * S + kt * 64 + c0;
      *(f16x8*)&vt[r * LP + c0] = *(const f16x8*)g;
      *(f16x8*)&vt[r * LP + c0 + 8] = *(const f16x8*)(g + 8);
    }
    __syncthreads();

    // S^T[kv][q]: A=K (m=kv), B=Q^T
    f32x4 sc[4][2];
#pragma unroll
    for (int mt = 0; mt < 4; ++mt)
#pragma unroll
      for (int nt = 0; nt < 2; ++nt) sc[mt][nt] = (f32x4){0.f, 0.f, 0.f, 0.f};
#pragma unroll
    for (int kc = 0; kc < 4; ++kc) {
      f16x4 ka[4];
#pragma unroll
      for (int mt = 0; mt < 4; ++mt)
        ka[mt] = *(const f16x4*)&ks[(mt * 16 + l15) * LP + kc * 16 + quad * 4];
#pragma unroll
      for (int mt = 0; mt < 4; ++mt)
#pragma unroll
        for (int nt = 0; nt < 2; ++nt)
          sc[mt][nt] = MFMA16(ka[mt], qf[nt][kc], sc[mt][nt]);
    }

    // P^T = exp2(S^T) in registers; C-layout == next B-layout. l accumulates in VALU.
    f16x4 pb[4][2];
#pragma unroll
    for (int mt = 0; mt < 4; ++mt)
#pragma unroll
      for (int nt = 0; nt < 2; ++nt) {
        const float p0 = __builtin_amdgcn_exp2f(sc[mt][nt][0]);
        const float p1 = __builtin_amdgcn_exp2f(sc[mt][nt][1]);
        const float p2 = __builtin_amdgcn_exp2f(sc[mt][nt][2]);
        const float p3 = __builtin_amdgcn_exp2f(sc[mt][nt][3]);
        lsum[nt] += (p0 + p1) + (p2 + p3);
        pb[mt][nt] = cvt4(p0, p1, p2, p3);
      }

    // O^T += V^T · P^T : A = V^T (m=d, k=kv), B = pb
#pragma unroll
    for (int mt = 0; mt < 4; ++mt) {
      f16x4 va[4];
#pragma unroll
      for (int dt = 0; dt < 4; ++dt)
        va[dt] = *(const f16x4*)&vt[(dt * 16 + l15) * LP + mt * 16 + quad * 4];
#pragma unroll
      for (int dt = 0; dt < 4; ++dt)
#pragma unroll
        for (int nt = 0; nt < 2; ++nt)
          Ot[dt][nt] = MFMA16(va[dt], pb[mt][nt], Ot[dt][nt]);
    }
  }

  // l: sum partial l across the 4 quads (each covered disjoint kv rows)
#pragma unroll
  for (int nt = 0; nt < 2; ++nt) {
    lsum[nt] += __shfl_xor(lsum[nt], 16, 64);
    lsum[nt] += __shfl_xor(lsum[nt], 32, 64);
  }

  const int b = bh >> 4, h = bh & 15;
#pragma unroll
  for (int nt = 0; nt < 2; ++nt) {
    const float inv = 1.f / lsum[nt];
    const int q = q0 + w * 32 + nt * 16 + l15;
    f16* o = ao + ((size_t)b * S + q) * E + h * 64;
#pragma unroll
    for (int dt = 0; dt < 4; ++dt) {
      const f16x4 pk = cvt4(Ot[dt][nt][0] * inv, Ot[dt][nt][1] * inv,
                            Ot[dt][nt][2] * inv, Ot[dt][nt][3] * inv);
      *(f16x4*)(o + dt * 16 + quad * 4) = pk;
    }
  }
}

// ---------- dense: out = A·Wd^T + bd. Tile 128m x 64n, grid 512, Wd converted in staging.
__global__ __launch_bounds__(256) void dense_mfma(const f16* __restrict__ A,
                                                  const float* __restrict__ Wd,
                                                  const float* __restrict__ bd,
                                                  float* __restrict__ out) {
  __shared__ f16 as[128 * LP];
  __shared__ f16 bs[64 * LP];
  const int t = threadIdx.x, lane = t & 63, w = t >> 6;
  const int l15 = lane & 15, quad = lane >> 4;
  const int m0 = blockIdx.x * 128, n0 = blockIdx.y * 64;
  const int wm = w * 32;

  f32x4 acc[2][4];
#pragma unroll
  for (int mt = 0; mt < 2; ++mt)
#pragma unroll
    for (int nt = 0; nt < 4; ++nt) acc[mt][nt] = (f32x4){0.f, 0.f, 0.f, 0.f};

  for (int kt = 0; kt < E / 64; ++kt) {
    __syncthreads();
    {  // A tile: 128 rows x 64 f16
      const int r = t >> 1, c0 = (t & 1) * 32;
      const f16* ga = A + (size_t)(m0 + r) * E + kt * 64 + c0;
#pragma unroll
      for (int c = 0; c < 4; ++c)
        *(f16x8*)&as[r * LP + c0 + 8 * c] = *(const f16x8*)(ga + 8 * c);
    }
    {  // Wd tile: 64 rows x 64, fp32 -> f16
      const int r = t >> 2, c0 = (t & 3) * 16;
      const float* gb = Wd + (size_t)(n0 + r) * E + kt * 64 + c0;
#pragma unroll
      for (int c = 0; c < 2; ++c) {
        const float4 a = *(const float4*)(gb + 8 * c), b2 = *(const float4*)(gb + 8 * c + 4);
        f16x8 v;
        v[0]=(f16)a.x; v[1]=(f16)a.y; v[2]=(f16)a.z; v[3]=(f16)a.w;
        v[4]=(f16)b2.x; v[5]=(f16)b2.y; v[6]=(f16)b2.z; v[7]=(f16)b2.w;
        *(f16x8*)&bs[r * LP + c0 + 8 * c] = v;
      }
    }
    __syncthreads();
    f16x8 af[2][2];
#pragma unroll
    for (int mt = 0; mt < 2; ++mt)
#pragma unroll
      for (int kc = 0; kc < 2; ++kc)
        af[mt][kc] = *(const f16x8*)&as[(wm + mt * 16 + l15) * LP + kc * 32 + quad * 8];
#pragma unroll
    for (int kc = 0; kc < 2; ++kc)
#pragma unroll
      for (int nt = 0; nt < 4; ++nt) {
        const f16x8 bf = *(const f16x8*)&bs[(nt * 16 + l15) * LP + kc * 32 + quad * 8];
#pragma unroll
        for (int mt = 0; mt < 2; ++mt)
          acc[mt][nt] = MFMA32(af[mt][kc], bf, acc[mt][nt]);
      }
  }
#pragma unroll
  for (int nt = 0; nt < 4; ++nt) {
    const int col = n0 + nt * 16 + l15;
    const float bdv = bd[col];
#pragma unroll
    for (int mt = 0; mt < 2; ++mt)
#pragma unroll
      for (int r = 0; r < 4; ++r)
        out[(size_t)(m0 + wm + mt * 16 + quad * 4 + r) * E + col] = acc[mt][nt][r] + bdv;
  }
}

extern "C" void kernel_launch(void* const* d_in, const int* in_sizes, int n_in,
                              void* d_out, int out_size, void* d_ws, size_t ws_size,
                              hipStream_t stream) {
  const float* queries = (const float*)d_in[0];
  const float* values  = (const float*)d_in[1];
  const float* Wv = (const float*)d_in[3];
  const float* bv = (const float*)d_in[4];
  const float* Wk = (const float*)d_in[5];
  const float* bk = (const float*)d_in[6];
  const float* Wq = (const float*)d_in[7];
  const float* bq = (const float*)d_in[8];
  const float* Wd = (const float*)d_in[9];
  const float* bd = (const float*)d_in[10];
  float* out = (float*)d_out;

  char* ws = (char*)d_ws;
  f16* qp  = (f16*)(ws);                       // 8 MB [B,H,S,D] (pre-scaled by QSCALE)
  f16* kp  = (f16*)(ws + 8u * 1024 * 1024);    // 8 MB [B,H,S,D]
  f16* vtg = (f16*)(ws + 16u * 1024 * 1024);   // 8 MB [B,H,D,S]  (V transposed)
  f16* ao  = (f16*)(ws + 24u * 1024 * 1024);   // 8 MB [B,S,E]
  (void)ws_size; (void)in_sizes; (void)n_in; (void)out_size;

  proj_q<<<512, 256, 0, stream>>>(queries, Wq, bq, qp);
  proj_vk<<<dim3(B * H, S / 128), 256, 0, stream>>>(values, Wv, bv, Wk, bk, vtg, kp);
  attn_mfma<<<dim3(B * H, S / 128), 256, 0, stream>>>(qp, kp, vtg, ao);
  dense_mfma<<<dim3(B * S / 128, E / 64), 256, 0, stream>>>(ao, Wd, bd, out);
}